// Round 13
// baseline (499.681 us; speedup 1.0000x reference)
//
#include <hip/hip_runtime.h>
#include <hip/hip_bf16.h>

#define N_NODES 100000
#define N_EDGES 1600000
#define BN_EPS 1e-5f
#define SCAN_BLOCKS 391   // ceil(100000/256)

typedef __hip_bfloat16 bf16;
typedef unsigned long long ull;
typedef float v2f __attribute__((ext_vector_type(2)));

__device__ __forceinline__ float b2f(bf16 v) { return __bfloat162float(v); }
__device__ __forceinline__ float frcp(float x) { return __builtin_amdgcn_rcpf(x); }
__device__ __forceinline__ float fsig(float x) { return frcp(1.0f + __expf(-x)); }
__device__ __forceinline__ float ftanh(float x) {
    return 1.0f - 2.0f * frcp(__expf(2.0f * x) + 1.0f);
}
__device__ __forceinline__ float bfr(uint u) { return __uint_as_float(u << 16); }
__device__ __forceinline__ v2f up(uint u) {
    return (v2f){__uint_as_float(u << 16), __uint_as_float(u & 0xffff0000u)};
}
__device__ __forceinline__ v2f vfma(v2f a, v2f b, v2f c) {
    return __builtin_elementwise_fma(a, b, c);
}
__device__ __forceinline__ uint pk2(const float* p) {
    bf16 a = __float2bfloat16(p[0]), b = __float2bfloat16(p[1]);
    return (uint)*(ushort*)&a | ((uint)*(ushort*)&b << 16);
}
__device__ __forceinline__ uint pkv(v2f v) {
    bf16 a = __float2bfloat16(v.x), b = __float2bfloat16(v.y);
    return (uint)*(ushort*)&a | ((uint)*(ushort*)&b << 16);
}

// ---- utility ---------------------------------------------------------------
__global__ void k_zero_f(float* __restrict__ p, int n) {
    int i = blockIdx.x * 256 + threadIdx.x;
    if (i < n) p[i] = 0.f;
}
__global__ void k_marker(float* __restrict__ p, int n, float v) {
    int i = blockIdx.x * 256 + threadIdx.x;
    if (i < n) p[i] = v;
}

// ---- packed histogram: pk[d] += (1<<48)|fx(ew); rank = old count -----------
__global__ void k_hist(const int* __restrict__ ei, const float* __restrict__ ew,
                       ull* __restrict__ pk, int* __restrict__ rank) {
    int e = blockIdx.x * 256 + threadIdx.x;
    if (e < N_EDGES) {
        int d = ei[N_EDGES + e];
        ull v = (1ull << 48) | (ull)((double)ew[e] * 4294967296.0);
        ull old = atomicAdd(&pk[d], v);
        rank[e] = (int)(old >> 48);
    }
}

// ---- parallel scan, stage 1: per-block sums of counts ----------------------
__global__ void k_bsum(const ull* __restrict__ pk, int* __restrict__ bsum) {
    __shared__ int s[256];
    int idx = blockIdx.x * 256 + threadIdx.x;
    s[threadIdx.x] = (idx < N_NODES) ? (int)(pk[idx] >> 48) : 0;
    __syncthreads();
    for (int st = 128; st >= 1; st >>= 1) {
        if (threadIdx.x < st) s[threadIdx.x] += s[threadIdx.x + st];
        __syncthreads();
    }
    if (threadIdx.x == 0) bsum[blockIdx.x] = s[0];
}

// ---- stage 2: exclusive scan of 391 block sums (single tiny block) ---------
__global__ __launch_bounds__(512) void k_bscan(const int* __restrict__ bsum,
                                               int* __restrict__ bbase) {
    __shared__ int s[512];
    int t = threadIdx.x;
    int v = (t < SCAN_BLOCKS) ? bsum[t] : 0;
    s[t] = v; __syncthreads();
    for (int st = 1; st < 512; st <<= 1) {
        int u = (t >= st) ? s[t - st] : 0;
        __syncthreads();
        s[t] += u;
        __syncthreads();
    }
    if (t < SCAN_BLOCKS) bbase[t] = s[t] - v;   // exclusive prefix
}

// ---- stage 3: block scan -> off; unpack deg from pk ------------------------
__global__ void k_scan3(const ull* __restrict__ pk, const int* __restrict__ bbase,
                        int* __restrict__ off, float* __restrict__ deg) {
    __shared__ int wsum[4];
    int idx = blockIdx.x * 256 + threadIdx.x;
    int lane = threadIdx.x & 63, w = threadIdx.x >> 6;
    ull pv = (idx < N_NODES) ? pk[idx] : 0ull;
    int c = (int)(pv >> 48);
    int s = c;
    for (int d = 1; d < 64; d <<= 1) {
        int u = __shfl_up(s, d, 64);
        if (lane >= d) s += u;
    }
    if (lane == 63) wsum[w] = s;
    __syncthreads();
    int wb = 0;
    for (int i = 0; i < w; i++) wb += wsum[i];
    int e = bbase[blockIdx.x] + wb + s - c;      // exclusive
    if (idx < N_NODES) {
        off[idx] = e;
        deg[idx] = (float)((double)(pv & 0xFFFFFFFFFFFFull) * (1.0 / 4294967296.0));
    }
    if (idx == 0) off[N_NODES] = N_EDGES;        // all dst are in-range
}

// ---- scatter edges into CSR slots as {src, norm} — NO atomics --------------
__global__ void k_scatter(const int* __restrict__ ei, const float* __restrict__ ew,
                          const float* __restrict__ deg, const int* __restrict__ off,
                          const int* __restrict__ rank, int2* __restrict__ epk) {
    int e = blockIdx.x * 256 + threadIdx.x;
    if (e < N_EDGES) {
        int s = ei[e], d = ei[N_EDGES + e];
        float nm = ew[e] * rsqrtf((deg[s] + 1.0f) * (deg[d] + 1.0f));
        epk[off[d] + rank[e]] = make_int2(s, __float_as_int(nm));
    }
}

// ---- column sums of x (for skip_avg) ---------------------------------------
__global__ void k_xmean(const float* __restrict__ x, float* __restrict__ xsum) {
    __shared__ float s[256];
    int f = threadIdx.x & 31, rg = threadIdx.x >> 5;
    float acc = 0.f;
    for (int n = blockIdx.x * 8 + rg; n < N_NODES; n += gridDim.x * 8)
        acc += x[n * 32 + f];
    s[threadIdx.x] = acc; __syncthreads();
    for (int st = 128; st >= 32; st >>= 1) {
        if (threadIdx.x < st) s[threadIdx.x] += s[threadIdx.x + st];
        __syncthreads();
    }
    if (threadIdx.x < 32) atomicAdd(&xsum[threadIdx.x], s[threadIdx.x]);
}

// ---- A = x @ W1 (fp32 in, bf16 out) ----------------------------------------
__global__ void k_xw1(const float* __restrict__ x, const float* __restrict__ w,
                      bf16* __restrict__ A) {
    __shared__ float Ws[32 * 33];
    __shared__ float xs[256];
    for (int i = threadIdx.x; i < 1024; i += 256)
        Ws[(i >> 5) * 33 + (i & 31)] = w[i];
    long base = (long)blockIdx.x * 256;
    xs[threadIdx.x] = x[base + threadIdx.x];
    __syncthreads();
    int r = threadIdx.x >> 5, h = threadIdx.x & 31;
    float acc = 0.f;
#pragma unroll
    for (int f = 0; f < 32; f++) acc += xs[r * 32 + f] * Ws[f * 33 + h];
    A[base + threadIdx.x] = __float2bfloat16(acc);
}

// ---- pull-mode GCN: 16 lanes/node, uint gathers, 8 chains in flight --------
__global__ __launch_bounds__(256) void k_gcn(
    const int* __restrict__ off, const int2* __restrict__ epk,
    const bf16* __restrict__ A, const float* __restrict__ deg,
    const float* __restrict__ bias, bf16* __restrict__ B,
    float* __restrict__ sum, float* __restrict__ sq) {
    __shared__ v2f s1[256], s2[256];
    const uint* Au = (const uint*)A;
    uint* Bu = (uint*)B;
    int tid = threadIdx.x, fp = tid & 15, g = tid >> 4;
    v2f bv = (v2f){bias[2 * fp], bias[2 * fp + 1]};
    v2f a1 = (v2f)0.f, a2 = (v2f)0.f;
    for (int n = blockIdx.x * 16 + g; n < N_NODES; n += gridDim.x * 16) {
        int lo = off[n], hi = off[n + 1];
        v2f acc0 = (v2f)0.f, acc1 = (v2f)0.f, acc2 = (v2f)0.f, acc3 = (v2f)0.f;
        v2f acc4 = (v2f)0.f, acc5 = (v2f)0.f, acc6 = (v2f)0.f, acc7 = (v2f)0.f;
        int p = lo;
        for (; p + 7 < hi; p += 8) {
            int2 e0 = epk[p],     e1 = epk[p + 1], e2 = epk[p + 2], e3 = epk[p + 3];
            int2 e4 = epk[p + 4], e5 = epk[p + 5], e6 = epk[p + 6], e7 = epk[p + 7];
            uint a0 = Au[(long)e0.x * 16 + fp], a1u = Au[(long)e1.x * 16 + fp];
            uint a2u = Au[(long)e2.x * 16 + fp], a3 = Au[(long)e3.x * 16 + fp];
            uint a4 = Au[(long)e4.x * 16 + fp], a5 = Au[(long)e5.x * 16 + fp];
            uint a6 = Au[(long)e6.x * 16 + fp], a7 = Au[(long)e7.x * 16 + fp];
            float n0 = __int_as_float(e0.y), n1 = __int_as_float(e1.y);
            float n2 = __int_as_float(e2.y), n3 = __int_as_float(e3.y);
            float n4 = __int_as_float(e4.y), n5 = __int_as_float(e5.y);
            float n6 = __int_as_float(e6.y), n7 = __int_as_float(e7.y);
            acc0 = vfma(up(a0), (v2f){n0, n0}, acc0);
            acc1 = vfma(up(a1u), (v2f){n1, n1}, acc1);
            acc2 = vfma(up(a2u), (v2f){n2, n2}, acc2);
            acc3 = vfma(up(a3), (v2f){n3, n3}, acc3);
            acc4 = vfma(up(a4), (v2f){n4, n4}, acc4);
            acc5 = vfma(up(a5), (v2f){n5, n5}, acc5);
            acc6 = vfma(up(a6), (v2f){n6, n6}, acc6);
            acc7 = vfma(up(a7), (v2f){n7, n7}, acc7);
        }
        for (; p + 3 < hi; p += 4) {
            int2 e0 = epk[p], e1 = epk[p + 1], e2 = epk[p + 2], e3 = epk[p + 3];
            float n0 = __int_as_float(e0.y), n1 = __int_as_float(e1.y);
            float n2 = __int_as_float(e2.y), n3 = __int_as_float(e3.y);
            acc0 = vfma(up(Au[(long)e0.x * 16 + fp]), (v2f){n0, n0}, acc0);
            acc1 = vfma(up(Au[(long)e1.x * 16 + fp]), (v2f){n1, n1}, acc1);
            acc2 = vfma(up(Au[(long)e2.x * 16 + fp]), (v2f){n2, n2}, acc2);
            acc3 = vfma(up(Au[(long)e3.x * 16 + fp]), (v2f){n3, n3}, acc3);
        }
        for (; p < hi; p++) {
            int2 e0 = epk[p];
            float n0 = __int_as_float(e0.y);
            acc0 = vfma(up(Au[(long)e0.x * 16 + fp]), (v2f){n0, n0}, acc0);
        }
        float si = frcp(deg[n] + 1.0f);
        v2f v = vfma(up(Au[(long)n * 16 + fp]), (v2f){si, si},
                     ((acc0 + acc1) + (acc2 + acc3)) +
                     ((acc4 + acc5) + (acc6 + acc7))) + bv;
        v.x = fmaxf(v.x, 0.f); v.y = fmaxf(v.y, 0.f);
        Bu[(long)n * 16 + fp] = pkv(v);
        a1 += v; a2 += v * v;
    }
    s1[tid] = a1; s2[tid] = a2; __syncthreads();
    for (int st = 128; st >= 16; st >>= 1) {
        if (tid < st) { s1[tid] += s1[tid + st]; s2[tid] += s2[tid + st]; }
        __syncthreads();
    }
    if (tid < 16) {
        atomicAdd(&sum[2 * tid], s1[tid].x); atomicAdd(&sum[2 * tid + 1], s1[tid].y);
        atomicAdd(&sq[2 * tid], s2[tid].x);  atomicAdd(&sq[2 * tid + 1], s2[tid].y);
    }
}

// ---- BN1 finalize ----------------------------------------------------------
__global__ void k_fin1(const float* __restrict__ sum, const float* __restrict__ sq,
                       const float* __restrict__ g, const float* __restrict__ be,
                       float* __restrict__ scale, float* __restrict__ shift) {
    int t = threadIdx.x;
    if (t < 32) {
        float mu = sum[t] / (float)N_NODES;
        float var = sq[t] / (float)N_NODES - mu * mu;
        float rs = rsqrtf(var + BN_EPS) * g[t];
        scale[t] = rs;
        shift[t] = be[t] - mu * rs;
    }
}

// ---- H = affine(B) (bf16); A = H @ W2 (bf16) -------------------------------
__global__ void k_aff_xw(const bf16* __restrict__ B, const float* __restrict__ scale,
                         const float* __restrict__ shift, const float* __restrict__ w,
                         bf16* __restrict__ H, bf16* __restrict__ A) {
    __shared__ float Ws[32 * 33];
    __shared__ float hs[256];
    for (int i = threadIdx.x; i < 1024; i += 256)
        Ws[(i >> 5) * 33 + (i & 31)] = w[i];
    long base = (long)blockIdx.x * 256;
    int f = threadIdx.x & 31;
    float h = b2f(B[base + threadIdx.x]) * scale[f] + shift[f];
    H[base + threadIdx.x] = __float2bfloat16(h);
    hs[threadIdx.x] = h;
    __syncthreads();
    int r = threadIdx.x >> 5, hc = threadIdx.x & 31;
    float acc = 0.f;
#pragma unroll
    for (int k = 0; k < 32; k++) acc += hs[r * 32 + k] * Ws[k * 33 + hc];
    A[base + threadIdx.x] = __float2bfloat16(acc);
}

// ---- BN2 finalize + fc1 const + combined LSTM biases -----------------------
__global__ void k_fin2(const float* __restrict__ sum, const float* __restrict__ sq,
                       const float* __restrict__ g, const float* __restrict__ be,
                       const float* __restrict__ xsum, const float* __restrict__ fw1,
                       const float* __restrict__ fb1,
                       const float* __restrict__ bih1, const float* __restrict__ bhh1,
                       const float* __restrict__ bih2, const float* __restrict__ bhh2,
                       float* __restrict__ scale, float* __restrict__ shift,
                       float* __restrict__ fc1c, float* __restrict__ lb1,
                       float* __restrict__ lb2) {
    int t = threadIdx.x;
    if (t < 32) {
        float mu = sum[t] / (float)N_NODES;
        float var = sq[t] / (float)N_NODES - mu * mu;
        float rs = rsqrtf(var + BN_EPS) * g[t];
        scale[t] = rs;
        shift[t] = be[t] - mu * rs;
        float c = fb1[t];
        for (int f = 0; f < 32; f++)
            c += (xsum[f] / (float)N_NODES) * fw1[t * 96 + 64 + f];
        fc1c[t] = c;
    }
    if (t < 128) {
        lb1[t] = bih1[t] + bhh1[t];
        lb2[t] = bih2[t] + bhh2[t];
    }
}

// ---- per-node dense stack: 4 THREADS PER NODE, XOR-swizzled exchange -------
__global__ __launch_bounds__(256) void k_final(
    const bf16* __restrict__ Hb, const bf16* __restrict__ Bb,
    const float* __restrict__ scale2, const float* __restrict__ shift2,
    const float* __restrict__ wih1, const float* __restrict__ wih2,
    const float* __restrict__ fw1, const float* __restrict__ fw2,
    const float* __restrict__ fb2,
    const float* __restrict__ fc1c, const float* __restrict__ lb1,
    const float* __restrict__ lb2, float* __restrict__ out) {
    __shared__ uint4 Wa4[780];   // LSTM1: gate t*260 + (c>>3)*65 + (c&7)*8 + q
    __shared__ uint4 Wb4[384];   // LSTM2: t*128 + c*4 + q (dense, swizzle-safe)
    __shared__ uint4 Fc4[256];   // fc1: j*8 + colu (dense, swizzle-safe)
    __shared__ float lb1s[128], lb2s[128], fc1s[32], fw2s[32], sc2[32], sh2[32];
    int tid = threadIdx.x;
    for (int l = tid; l < 768; l += 256) {
        int t = l >> 8, rem = l & 255, c = rem >> 3, q = rem & 7;
        int row = (t == 0) ? c : ((t == 1) ? c + 64 : c + 96);
        const float* b = wih1 + row * 64 + q * 8;
        Wa4[t * 260 + (c >> 3) * 65 + (c & 7) * 8 + q] =
            make_uint4(pk2(b), pk2(b + 2), pk2(b + 4), pk2(b + 6));
    }
    for (int i = tid; i < 384; i += 256) {
        int t = i >> 7, rem = i & 127, c = rem >> 2, q = rem & 3;
        int row = (t == 0) ? c : ((t == 1) ? c + 64 : c + 96);
        const float* b = wih2 + row * 32 + q * 8;
        Wb4[i] = make_uint4(pk2(b), pk2(b + 2), pk2(b + 4), pk2(b + 6));
    }
    for (int i = tid; i < 256; i += 256) {
        int j = i >> 3, q = i & 7;
        const float* b = fw1 + j * 96 + q * 8;
        Fc4[i] = make_uint4(pk2(b), pk2(b + 2), pk2(b + 4), pk2(b + 6));
    }
    if (tid < 128) { lb1s[tid] = lb1[tid]; lb2s[tid] = lb2[tid]; }
    if (tid >= 128 && tid < 160) {
        int t = tid - 128;
        fc1s[t] = fc1c[t]; fw2s[t] = fw2[t];
        sc2[t] = scale2[t]; sh2[t] = shift2[t];
    }
    __syncthreads();
    int Q = tid & 3;
    int n = blockIdx.x * 64 + (tid >> 2);
    if (n >= N_NODES) return;

    v2f cat2[32];
    {
        const uint4* Hv = (const uint4*)((const ushort*)Hb + (long)n * 32);
        const uint4* Bv = (const uint4*)((const ushort*)Bb + (long)n * 32);
#pragma unroll
        for (int q = 0; q < 4; q++) {
            uint4 hu = Hv[q], bu = Bv[q];
            uint hw[4] = {hu.x, hu.y, hu.z, hu.w};
            uint bw[4] = {bu.x, bu.y, bu.z, bu.w};
#pragma unroll
            for (int r = 0; r < 4; r++) {
                int u = q * 4 + r;
                int e0 = 2 * u, e1 = 2 * u + 1;
                cat2[u] = up(hw[r]);
                cat2[16 + u] = vfma(up(bw[r]),
                                    (v2f){sc2[e0], sc2[e1]},
                                    (v2f){sh2[e0], sh2[e1]});
            }
        }
    }
    // ---- LSTM1: my 8 channels --------------------------------------------
    float my1[8];
#pragma unroll
    for (int ci = 0; ci < 8; ci++) {
        int rb = Q * 65 + ci * 8;
        v2f ai = (v2f)0.f, ag = (v2f)0.f, ao = (v2f)0.f;
#pragma unroll
        for (int q = 0; q < 8; q++) {
            uint4 wi = Wa4[rb + q], wg = Wa4[260 + rb + q], wo = Wa4[520 + rb + q];
            uint wiw[4] = {wi.x, wi.y, wi.z, wi.w};
            uint wgw[4] = {wg.x, wg.y, wg.z, wg.w};
            uint wow[4] = {wo.x, wo.y, wo.z, wo.w};
#pragma unroll
            for (int r = 0; r < 4; r++) {
                v2f x0 = cat2[q * 4 + r];
                ai = vfma(up(wiw[r]), x0, ai);
                ag = vfma(up(wgw[r]), x0, ag);
                ao = vfma(up(wow[r]), x0, ao);
            }
        }
        int c = Q * 8 + ci;
        float gi = ai.x + ai.y + lb1s[c];
        float gg = ag.x + ag.y + lb1s[64 + c];
        float go = ao.x + ao.y + lb1s[96 + c];
        float c1 = fsig(gi) * ftanh(gg);
        my1[ci] = fsig(go) * ftanh(c1);
    }
    // ---- exchange to XOR-relative full h1 ----------------------------------
    v2f h1r[16];
#pragma unroll
    for (int i = 0; i < 8; i++) {
        float v0 = my1[i];
        float v1 = __shfl_xor(v0, 1);
        float v2 = __shfl_xor(v0, 2);
        float v3 = __shfl_xor(v1, 2);
        h1r[i >> 1][i & 1] = v0;
        h1r[4 + (i >> 1)][i & 1] = v1;
        h1r[8 + (i >> 1)][i & 1] = v2;
        h1r[12 + (i >> 1)][i & 1] = v3;
    }
    // ---- LSTM2 -------------------------------------------------------------
    float my2[8];
#pragma unroll
    for (int ci = 0; ci < 8; ci++) {
        int c = Q * 8 + ci;
        v2f ai = (v2f)0.f, ag = (v2f)0.f, ao = (v2f)0.f;
#pragma unroll
        for (int a = 0; a < 4; a++) {
            int idx = c * 4 + (Q ^ a);
            uint4 wi = Wb4[idx], wg = Wb4[128 + idx], wo = Wb4[256 + idx];
            uint wiw[4] = {wi.x, wi.y, wi.z, wi.w};
            uint wgw[4] = {wg.x, wg.y, wg.z, wg.w};
            uint wow[4] = {wo.x, wo.y, wo.z, wo.w};
#pragma unroll
            for (int r = 0; r < 4; r++) {
                v2f x0 = h1r[a * 4 + r];
                ai = vfma(up(wiw[r]), x0, ai);
                ag = vfma(up(wgw[r]), x0, ag);
                ao = vfma(up(wow[r]), x0, ao);
            }
        }
        float gi = ai.x + ai.y + lb2s[c];
        float gg = ag.x + ag.y + lb2s[64 + c];
        float go = ao.x + ao.y + lb2s[96 + c];
        float c2 = fsig(gi) * ftanh(gg);
        my2[ci] = fsig(go) * ftanh(c2);
    }
    v2f h2r[16];
#pragma unroll
    for (int i = 0; i < 8; i++) {
        float v0 = my2[i];
        float v1 = __shfl_xor(v0, 1);
        float v2 = __shfl_xor(v0, 2);
        float v3 = __shfl_xor(v1, 2);
        h2r[i >> 1][i & 1] = v0;
        h2r[4 + (i >> 1)][i & 1] = v1;
        h2r[8 + (i >> 1)][i & 1] = v2;
        h2r[12 + (i >> 1)][i & 1] = v3;
    }
    // ---- fc1(relu) @ fc2: my 8 rows, quad-reduce ---------------------------
    float acc = 0.f;
#pragma unroll
    for (int ji = 0; ji < 8; ji++) {
        int j = Q * 8 + ji;
        v2f z = (v2f)0.f;
#pragma unroll
        for (int a = 0; a < 4; a++) {
            int colu = Q ^ a;
            uint4 wA = Fc4[j * 8 + colu];
            uint4 wB = Fc4[j * 8 + 4 + colu];
            uint wa[4] = {wA.x, wA.y, wA.z, wA.w};
            uint wb[4] = {wB.x, wB.y, wB.z, wB.w};
#pragma unroll
            for (int r = 0; r < 4; r++) {
                z = vfma(up(wa[r]), h1r[a * 4 + r], z);
                z = vfma(up(wb[r]), h2r[a * 4 + r], z);
            }
        }
        float zz = z.x + z.y + fc1s[j];
        acc += fmaxf(zz, 0.f) * fw2s[j];
    }
    acc += __shfl_xor(acc, 1);
    acc += __shfl_xor(acc, 2);
    if (Q == 0) out[n] = acc + fb2[0];
}

extern "C" void kernel_launch(void* const* d_in, const int* in_sizes, int n_in,
                              void* d_out, int out_size, void* d_ws, size_t ws_size,
                              hipStream_t stream) {
    const float* x    = (const float*)d_in[0];
    const int*   ei   = (const int*)d_in[1];
    const float* ew   = (const float*)d_in[2];
    const float* w1   = (const float*)d_in[3];
    const float* b1   = (const float*)d_in[4];
    const float* g1   = (const float*)d_in[5];
    const float* be1  = (const float*)d_in[6];
    const float* w2   = (const float*)d_in[7];
    const float* b2   = (const float*)d_in[8];
    const float* g2   = (const float*)d_in[9];
    const float* be2  = (const float*)d_in[10];
    const float* wih1 = (const float*)d_in[11];
    const float* bih1 = (const float*)d_in[13];
    const float* bhh1 = (const float*)d_in[14];
    const float* wih2 = (const float*)d_in[15];
    const float* bih2 = (const float*)d_in[17];
    const float* bhh2 = (const float*)d_in[18];
    const float* fw1  = (const float*)d_in[19];
    const float* fb1  = (const float*)d_in[20];
    const float* fw2  = (const float*)d_in[21];
    const float* fb2  = (const float*)d_in[22];
    float* out = (float*)d_out;

    // ---- workspace layout (40.5 MB; proven ws >= 41.1 MB from r3/r4) -------
    char* ws = (char*)d_ws;
    float* stats = (float*)ws;                          // 576 floats @ 0
    float* xsum   = stats + 0;
    float* bn1sum = stats + 32;
    float* bn1sq  = stats + 64;
    float* bn2sum = stats + 96;
    float* bn2sq  = stats + 128;
    float* scale1 = stats + 160;
    float* shift1 = stats + 192;
    float* scale2 = stats + 224;
    float* shift2 = stats + 256;
    float* fc1c   = stats + 288;
    float* lb1    = stats + 320;
    float* lb2    = stats + 448;
    ull*   pk    = (ull*)  (ws + 4096);                 // 100000 ull -> 804,096
    int*   bsum  = (int*)  (ws + 804096);               // 391 i
    int*   bbase = (int*)  (ws + 808192);               // 391 i
    int*   off   = (int*)  (ws + 1048576);              // 100001 i -> 1,448,580
    float* deg   = (float*)(ws + 1572864);              // 100000 f -> 1,972,864
    int2*  epk   = (int2*) (ws + 2097152);              // 1.6M int2 -> 14,897,152
    int*   rank  = (int*)  (ws + 14897152);             // 1.6M i -> 21,297,152
    bf16*  A     = (bf16*) (ws + 21297152);             // 6.4MB -> 27,697,152
    bf16*  H     = (bf16*) (ws + 27697152);             // 6.4MB -> 34,097,152
    bf16*  B     = (bf16*) (ws + 34097152);             // 6.4MB -> 40,497,152

    if (ws_size < 40497152ull) {
        k_marker<<<(N_NODES + 255) / 256, 256, 0, stream>>>(out, N_NODES, 911.f);
        return;
    }

    // zero stats + pk in one shot (bytes 0 .. 804,096)
    k_zero_f<<<786, 256, 0, stream>>>(stats, 201024);

    k_hist<<<6250, 256, 0, stream>>>(ei, ew, pk, rank);
    k_bsum<<<SCAN_BLOCKS, 256, 0, stream>>>(pk, bsum);
    k_bscan<<<1, 512, 0, stream>>>(bsum, bbase);
    k_scan3<<<SCAN_BLOCKS, 256, 0, stream>>>(pk, bbase, off, deg);
    k_scatter<<<6250, 256, 0, stream>>>(ei, ew, deg, off, rank, epk);
    k_xmean<<<400, 256, 0, stream>>>(x, xsum);
    k_xw1<<<12500, 256, 0, stream>>>(x, w1, A);
    k_gcn<<<2048, 256, 0, stream>>>(off, epk, A, deg, b1, B, bn1sum, bn1sq);
    k_fin1<<<1, 64, 0, stream>>>(bn1sum, bn1sq, g1, be1, scale1, shift1);
    k_aff_xw<<<12500, 256, 0, stream>>>(B, scale1, shift1, w2, H, A);
    k_gcn<<<2048, 256, 0, stream>>>(off, epk, A, deg, b2, B, bn2sum, bn2sq);
    k_fin2<<<1, 128, 0, stream>>>(bn2sum, bn2sq, g2, be2, xsum, fw1, fb1,
                                  bih1, bhh1, bih2, bhh2,
                                  scale2, shift2, fc1c, lb1, lb2);
    k_final<<<1563, 256, 0, stream>>>(H, B, scale2, shift2, wih1, wih2,
                                      fw1, fw2, fb2, fc1c, lb1, lb2, out);
}

// Round 14
// 453.895 us; speedup vs baseline: 1.1009x; 1.1009x over previous
//
#include <hip/hip_runtime.h>
#include <hip/hip_bf16.h>

#define N_NODES 100000
#define N_EDGES 1600000
#define BN_EPS 1e-5f
#define SCAN_BLOCKS 391   // ceil(100000/256)

typedef __hip_bfloat16 bf16;
typedef unsigned long long ull;
typedef float v2f __attribute__((ext_vector_type(2)));
typedef short bfrag __attribute__((ext_vector_type(8)));   // 8 bf16 = 4 VGPRs
typedef float f32x4 __attribute__((ext_vector_type(4)));

__device__ __forceinline__ float b2f(bf16 v) { return __bfloat162float(v); }
__device__ __forceinline__ float frcp(float x) { return __builtin_amdgcn_rcpf(x); }
__device__ __forceinline__ float fsig(float x) { return frcp(1.0f + __expf(-x)); }
__device__ __forceinline__ float ftanh(float x) {
    return 1.0f - 2.0f * frcp(__expf(2.0f * x) + 1.0f);
}
__device__ __forceinline__ float bfr(uint u) { return __uint_as_float(u << 16); }
__device__ __forceinline__ v2f up(uint u) {
    return (v2f){__uint_as_float(u << 16), __uint_as_float(u & 0xffff0000u)};
}
__device__ __forceinline__ v2f vfma(v2f a, v2f b, v2f c) {
    return __builtin_elementwise_fma(a, b, c);
}
__device__ __forceinline__ uint pk2(const float* p) {
    bf16 a = __float2bfloat16(p[0]), b = __float2bfloat16(p[1]);
    return (uint)*(ushort*)&a | ((uint)*(ushort*)&b << 16);
}
__device__ __forceinline__ uint pkv(v2f v) {
    bf16 a = __float2bfloat16(v.x), b = __float2bfloat16(v.y);
    return (uint)*(ushort*)&a | ((uint)*(ushort*)&b << 16);
}
#define LDS_FENCE() __asm__ volatile("s_waitcnt lgkmcnt(0)" ::: "memory")

// ---- utility ---------------------------------------------------------------
__global__ void k_zero_f(float* __restrict__ p, int n) {
    int i = blockIdx.x * 256 + threadIdx.x;
    if (i < n) p[i] = 0.f;
}
__global__ void k_marker(float* __restrict__ p, int n, float v) {
    int i = blockIdx.x * 256 + threadIdx.x;
    if (i < n) p[i] = v;
}

// ---- packed histogram: pk[d] += (1<<48)|fx(ew); rank = old count -----------
__global__ void k_hist(const int* __restrict__ ei, const float* __restrict__ ew,
                       ull* __restrict__ pk, int* __restrict__ rank) {
    int e = blockIdx.x * 256 + threadIdx.x;
    if (e < N_EDGES) {
        int d = ei[N_EDGES + e];
        ull v = (1ull << 48) | (ull)((double)ew[e] * 4294967296.0);
        ull old = atomicAdd(&pk[d], v);
        rank[e] = (int)(old >> 48);
    }
}

// ---- parallel scan, stage 1: per-block sums of counts ----------------------
__global__ void k_bsum(const ull* __restrict__ pk, int* __restrict__ bsum) {
    __shared__ int s[256];
    int idx = blockIdx.x * 256 + threadIdx.x;
    s[threadIdx.x] = (idx < N_NODES) ? (int)(pk[idx] >> 48) : 0;
    __syncthreads();
    for (int st = 128; st >= 1; st >>= 1) {
        if (threadIdx.x < st) s[threadIdx.x] += s[threadIdx.x + st];
        __syncthreads();
    }
    if (threadIdx.x == 0) bsum[blockIdx.x] = s[0];
}

// ---- stage 2: exclusive scan of 391 block sums (single tiny block) ---------
__global__ __launch_bounds__(512) void k_bscan(const int* __restrict__ bsum,
                                               int* __restrict__ bbase) {
    __shared__ int s[512];
    int t = threadIdx.x;
    int v = (t < SCAN_BLOCKS) ? bsum[t] : 0;
    s[t] = v; __syncthreads();
    for (int st = 1; st < 512; st <<= 1) {
        int u = (t >= st) ? s[t - st] : 0;
        __syncthreads();
        s[t] += u;
        __syncthreads();
    }
    if (t < SCAN_BLOCKS) bbase[t] = s[t] - v;   // exclusive prefix
}

// ---- stage 3: block scan -> off; unpack deg from pk ------------------------
__global__ void k_scan3(const ull* __restrict__ pk, const int* __restrict__ bbase,
                        int* __restrict__ off, float* __restrict__ deg) {
    __shared__ int wsum[4];
    int idx = blockIdx.x * 256 + threadIdx.x;
    int lane = threadIdx.x & 63, w = threadIdx.x >> 6;
    ull pv = (idx < N_NODES) ? pk[idx] : 0ull;
    int c = (int)(pv >> 48);
    int s = c;
    for (int d = 1; d < 64; d <<= 1) {
        int u = __shfl_up(s, d, 64);
        if (lane >= d) s += u;
    }
    if (lane == 63) wsum[w] = s;
    __syncthreads();
    int wb = 0;
    for (int i = 0; i < w; i++) wb += wsum[i];
    int e = bbase[blockIdx.x] + wb + s - c;      // exclusive
    if (idx < N_NODES) {
        off[idx] = e;
        deg[idx] = (float)((double)(pv & 0xFFFFFFFFFFFFull) * (1.0 / 4294967296.0));
    }
    if (idx == 0) off[N_NODES] = N_EDGES;        // all dst are in-range
}

// ---- scatter edges into CSR slots as {src, norm} — NO atomics --------------
__global__ void k_scatter(const int* __restrict__ ei, const float* __restrict__ ew,
                          const float* __restrict__ deg, const int* __restrict__ off,
                          const int* __restrict__ rank, int2* __restrict__ epk) {
    int e = blockIdx.x * 256 + threadIdx.x;
    if (e < N_EDGES) {
        int s = ei[e], d = ei[N_EDGES + e];
        float nm = ew[e] * rsqrtf((deg[s] + 1.0f) * (deg[d] + 1.0f));
        epk[off[d] + rank[e]] = make_int2(s, __float_as_int(nm));
    }
}

// ---- column sums of x (for skip_avg) ---------------------------------------
__global__ void k_xmean(const float* __restrict__ x, float* __restrict__ xsum) {
    __shared__ float s[256];
    int f = threadIdx.x & 31, rg = threadIdx.x >> 5;
    float acc = 0.f;
    for (int n = blockIdx.x * 8 + rg; n < N_NODES; n += gridDim.x * 8)
        acc += x[n * 32 + f];
    s[threadIdx.x] = acc; __syncthreads();
    for (int st = 128; st >= 32; st >>= 1) {
        if (threadIdx.x < st) s[threadIdx.x] += s[threadIdx.x + st];
        __syncthreads();
    }
    if (threadIdx.x < 32) atomicAdd(&xsum[threadIdx.x], s[threadIdx.x]);
}

// ---- A = x @ W1 (fp32 in, bf16 out) ----------------------------------------
__global__ void k_xw1(const float* __restrict__ x, const float* __restrict__ w,
                      bf16* __restrict__ A) {
    __shared__ float Ws[32 * 33];
    __shared__ float xs[256];
    for (int i = threadIdx.x; i < 1024; i += 256)
        Ws[(i >> 5) * 33 + (i & 31)] = w[i];
    long base = (long)blockIdx.x * 256;
    xs[threadIdx.x] = x[base + threadIdx.x];
    __syncthreads();
    int r = threadIdx.x >> 5, h = threadIdx.x & 31;
    float acc = 0.f;
#pragma unroll
    for (int f = 0; f < 32; f++) acc += xs[r * 32 + f] * Ws[f * 33 + h];
    A[base + threadIdx.x] = __float2bfloat16(acc);
}

// ---- pull-mode GCN: 16 lanes/node, uint gathers, 8 chains in flight --------
__global__ __launch_bounds__(256) void k_gcn(
    const int* __restrict__ off, const int2* __restrict__ epk,
    const bf16* __restrict__ A, const float* __restrict__ deg,
    const float* __restrict__ bias, bf16* __restrict__ B,
    float* __restrict__ sum, float* __restrict__ sq) {
    __shared__ v2f s1[256], s2[256];
    const uint* Au = (const uint*)A;
    uint* Bu = (uint*)B;
    int tid = threadIdx.x, fp = tid & 15, g = tid >> 4;
    v2f bv = (v2f){bias[2 * fp], bias[2 * fp + 1]};
    v2f a1 = (v2f)0.f, a2 = (v2f)0.f;
    for (int n = blockIdx.x * 16 + g; n < N_NODES; n += gridDim.x * 16) {
        int lo = off[n], hi = off[n + 1];
        v2f acc0 = (v2f)0.f, acc1 = (v2f)0.f, acc2 = (v2f)0.f, acc3 = (v2f)0.f;
        v2f acc4 = (v2f)0.f, acc5 = (v2f)0.f, acc6 = (v2f)0.f, acc7 = (v2f)0.f;
        int p = lo;
        for (; p + 7 < hi; p += 8) {
            int2 e0 = epk[p],     e1 = epk[p + 1], e2 = epk[p + 2], e3 = epk[p + 3];
            int2 e4 = epk[p + 4], e5 = epk[p + 5], e6 = epk[p + 6], e7 = epk[p + 7];
            uint a0 = Au[(long)e0.x * 16 + fp], a1u = Au[(long)e1.x * 16 + fp];
            uint a2u = Au[(long)e2.x * 16 + fp], a3 = Au[(long)e3.x * 16 + fp];
            uint a4 = Au[(long)e4.x * 16 + fp], a5 = Au[(long)e5.x * 16 + fp];
            uint a6 = Au[(long)e6.x * 16 + fp], a7 = Au[(long)e7.x * 16 + fp];
            float n0 = __int_as_float(e0.y), n1 = __int_as_float(e1.y);
            float n2 = __int_as_float(e2.y), n3 = __int_as_float(e3.y);
            float n4 = __int_as_float(e4.y), n5 = __int_as_float(e5.y);
            float n6 = __int_as_float(e6.y), n7 = __int_as_float(e7.y);
            acc0 = vfma(up(a0), (v2f){n0, n0}, acc0);
            acc1 = vfma(up(a1u), (v2f){n1, n1}, acc1);
            acc2 = vfma(up(a2u), (v2f){n2, n2}, acc2);
            acc3 = vfma(up(a3), (v2f){n3, n3}, acc3);
            acc4 = vfma(up(a4), (v2f){n4, n4}, acc4);
            acc5 = vfma(up(a5), (v2f){n5, n5}, acc5);
            acc6 = vfma(up(a6), (v2f){n6, n6}, acc6);
            acc7 = vfma(up(a7), (v2f){n7, n7}, acc7);
        }
        for (; p + 3 < hi; p += 4) {
            int2 e0 = epk[p], e1 = epk[p + 1], e2 = epk[p + 2], e3 = epk[p + 3];
            float n0 = __int_as_float(e0.y), n1 = __int_as_float(e1.y);
            float n2 = __int_as_float(e2.y), n3 = __int_as_float(e3.y);
            acc0 = vfma(up(Au[(long)e0.x * 16 + fp]), (v2f){n0, n0}, acc0);
            acc1 = vfma(up(Au[(long)e1.x * 16 + fp]), (v2f){n1, n1}, acc1);
            acc2 = vfma(up(Au[(long)e2.x * 16 + fp]), (v2f){n2, n2}, acc2);
            acc3 = vfma(up(Au[(long)e3.x * 16 + fp]), (v2f){n3, n3}, acc3);
        }
        for (; p < hi; p++) {
            int2 e0 = epk[p];
            float n0 = __int_as_float(e0.y);
            acc0 = vfma(up(Au[(long)e0.x * 16 + fp]), (v2f){n0, n0}, acc0);
        }
        float si = frcp(deg[n] + 1.0f);
        v2f v = vfma(up(Au[(long)n * 16 + fp]), (v2f){si, si},
                     ((acc0 + acc1) + (acc2 + acc3)) +
                     ((acc4 + acc5) + (acc6 + acc7))) + bv;
        v.x = fmaxf(v.x, 0.f); v.y = fmaxf(v.y, 0.f);
        Bu[(long)n * 16 + fp] = pkv(v);
        a1 += v; a2 += v * v;
    }
    s1[tid] = a1; s2[tid] = a2; __syncthreads();
    for (int st = 128; st >= 16; st >>= 1) {
        if (tid < st) { s1[tid] += s1[tid + st]; s2[tid] += s2[tid + st]; }
        __syncthreads();
    }
    if (tid < 16) {
        atomicAdd(&sum[2 * tid], s1[tid].x); atomicAdd(&sum[2 * tid + 1], s1[tid].y);
        atomicAdd(&sq[2 * tid], s2[tid].x);  atomicAdd(&sq[2 * tid + 1], s2[tid].y);
    }
}

// ---- BN1 finalize ----------------------------------------------------------
__global__ void k_fin1(const float* __restrict__ sum, const float* __restrict__ sq,
                       const float* __restrict__ g, const float* __restrict__ be,
                       float* __restrict__ scale, float* __restrict__ shift) {
    int t = threadIdx.x;
    if (t < 32) {
        float mu = sum[t] / (float)N_NODES;
        float var = sq[t] / (float)N_NODES - mu * mu;
        float rs = rsqrtf(var + BN_EPS) * g[t];
        scale[t] = rs;
        shift[t] = be[t] - mu * rs;
    }
}

// ---- H = affine(B) (bf16); A = H @ W2 (bf16) -------------------------------
__global__ void k_aff_xw(const bf16* __restrict__ B, const float* __restrict__ scale,
                         const float* __restrict__ shift, const float* __restrict__ w,
                         bf16* __restrict__ H, bf16* __restrict__ A) {
    __shared__ float Ws[32 * 33];
    __shared__ float hs[256];
    for (int i = threadIdx.x; i < 1024; i += 256)
        Ws[(i >> 5) * 33 + (i & 31)] = w[i];
    long base = (long)blockIdx.x * 256;
    int f = threadIdx.x & 31;
    float h = b2f(B[base + threadIdx.x]) * scale[f] + shift[f];
    H[base + threadIdx.x] = __float2bfloat16(h);
    hs[threadIdx.x] = h;
    __syncthreads();
    int r = threadIdx.x >> 5, hc = threadIdx.x & 31;
    float acc = 0.f;
#pragma unroll
    for (int k = 0; k < 32; k++) acc += hs[r * 32 + k] * Ws[k * 33 + hc];
    A[base + threadIdx.x] = __float2bfloat16(acc);
}

// ---- BN2 finalize + fc1 const + combined LSTM biases -----------------------
__global__ void k_fin2(const float* __restrict__ sum, const float* __restrict__ sq,
                       const float* __restrict__ g, const float* __restrict__ be,
                       const float* __restrict__ xsum, const float* __restrict__ fw1,
                       const float* __restrict__ fb1,
                       const float* __restrict__ bih1, const float* __restrict__ bhh1,
                       const float* __restrict__ bih2, const float* __restrict__ bhh2,
                       float* __restrict__ scale, float* __restrict__ shift,
                       float* __restrict__ fc1c, float* __restrict__ lb1,
                       float* __restrict__ lb2) {
    int t = threadIdx.x;
    if (t < 32) {
        float mu = sum[t] / (float)N_NODES;
        float var = sq[t] / (float)N_NODES - mu * mu;
        float rs = rsqrtf(var + BN_EPS) * g[t];
        scale[t] = rs;
        shift[t] = be[t] - mu * rs;
        float c = fb1[t];
        for (int f = 0; f < 32; f++)
            c += (xsum[f] / (float)N_NODES) * fw1[t * 96 + 64 + f];
        fc1c[t] = c;
    }
    if (t < 128) {
        lb1[t] = bih1[t] + bhh1[t];
        lb2[t] = bih2[t] + bhh2[t];
    }
}

// ---- per-node dense stack via MFMA ----------------------------------------
// 128 nodes/block, 4 waves, each wave owns 2 disjoint 16-node M-tiles.
// Stages (all mfma_f32_16x16x32_bf16): LSTM1 gates (6 N-tiles x 2 K-tiles),
// activations in C-layout regs (i,g,o of channel c land in same lane),
// hn1 -> LDS, LSTM2 (6x1), hn2 -> LDS, fc1 (2 N-tiles x 2 sources), epilogue.
// Layouts (verified, guide §3/m89/m120): A[m=lane&15][k=quad*8+j],
// B[k=quad*8+j][n=lane&15], C/D[row=quad*4+r][col=lane&15].
#define CATP 72   // cat row stride (bf16): 64 + 8 pad -> 2-way banks max
#define WP1  72
#define WP2  40
#define FP1  72
#define HP   40
__global__ __launch_bounds__(256) void k_final(
    const bf16* __restrict__ Hb, const bf16* __restrict__ Bb,
    const float* __restrict__ scale2, const float* __restrict__ shift2,
    const float* __restrict__ wih1, const float* __restrict__ wih2,
    const float* __restrict__ fw1, const float* __restrict__ fw2,
    const float* __restrict__ fb2,
    const float* __restrict__ fc1c, const float* __restrict__ lb1,
    const float* __restrict__ lb2, float* __restrict__ out) {
    __shared__ ushort cat[128 * CATP];
    __shared__ ushort W1s[96 * WP1];
    __shared__ ushort W2s[96 * WP2];
    __shared__ ushort F1s[32 * FP1];
    __shared__ ushort h1s[128 * HP];
    __shared__ ushort h2s[128 * HP];
    __shared__ float lb1s[128], lb2s[128], fc1s[32], fw2s[32], sc2[32], sh2[32];
    int tid = threadIdx.x;
    if (tid < 128) { lb1s[tid] = lb1[tid]; lb2s[tid] = lb2[tid]; }
    if (tid >= 128 && tid < 160) {
        int t = tid - 128;
        fc1s[t] = fc1c[t]; fw2s[t] = fw2[t];
        sc2[t] = scale2[t]; sh2[t] = shift2[t];
    }
    // W1s rows = gate-cols n: 0..31 -> wih1 row n (i), 32..63 -> 64+(n-32) (g),
    // 64..95 -> 96+(n-64) (o). Same mapping for W2s/wih2.
    for (int i = tid; i < 96 * 8; i += 256) {
        int row = i >> 3, q = i & 7;
        int c = row & 31, t = row >> 5;
        int srow = (t == 0) ? c : ((t == 1) ? 64 + c : 96 + c);
        const float* b = wih1 + srow * 64 + q * 8;
        *(uint4*)&W1s[row * WP1 + q * 8] =
            make_uint4(pk2(b), pk2(b + 2), pk2(b + 4), pk2(b + 6));
    }
    for (int i = tid; i < 96 * 4; i += 256) {
        int row = i >> 2, q = i & 3;
        int c = row & 31, t = row >> 5;
        int srow = (t == 0) ? c : ((t == 1) ? 64 + c : 96 + c);
        const float* b = wih2 + srow * 32 + q * 8;
        *(uint4*)&W2s[row * WP2 + q * 8] =
            make_uint4(pk2(b), pk2(b + 2), pk2(b + 4), pk2(b + 6));
    }
    for (int i = tid; i < 32 * 8; i += 256) {
        int row = i >> 3, q = i & 7;
        const float* b = fw1 + row * 96 + q * 8;
        *(uint4*)&F1s[row * FP1 + q * 8] =
            make_uint4(pk2(b), pk2(b + 2), pk2(b + 4), pk2(b + 6));
    }
    __syncthreads();
    // ---- stage cat[node][0..63] = [H | affine(B)] --------------------------
    {
        int ni = tid >> 1, hf = tid & 1;
        int node = blockIdx.x * 128 + ni;
        int nc = node < N_NODES ? node : N_NODES - 1;
        const uint4* src = (const uint4*)((const ushort*)(hf ? Bb : Hb) + (long)nc * 32);
        ushort* dst = &cat[ni * CATP + hf * 32];
        if (hf == 0) {
#pragma unroll
            for (int q = 0; q < 4; q++) *(uint4*)(dst + q * 8) = src[q];
        } else {
#pragma unroll
            for (int q = 0; q < 4; q++) {
                uint4 v = src[q];
                uint w[4] = {v.x, v.y, v.z, v.w};
                uint o[4];
#pragma unroll
                for (int r = 0; r < 4; r++) {
                    int e = q * 8 + r * 2;
                    o[r] = pkv(vfma(up(w[r]), (v2f){sc2[e], sc2[e + 1]},
                                    (v2f){sh2[e], sh2[e + 1]}));
                }
                *(uint4*)(dst + q * 8) = make_uint4(o[0], o[1], o[2], o[3]);
            }
        }
    }
    __syncthreads();
    // ---- compute: wave wv owns M-tiles wv*2, wv*2+1 ------------------------
    int l = tid & 63, wv = tid >> 6;
    int quad = l >> 4, mr = l & 15;
    float fb2v = fb2[0];
#pragma unroll
    for (int it = 0; it < 2; it++) {
        int mt = wv * 2 + it;
        int mb = mt * 16;
        // LSTM1 gates
        bfrag a0 = *(const bfrag*)&cat[(mb + mr) * CATP + quad * 8];
        bfrag a1 = *(const bfrag*)&cat[(mb + mr) * CATP + 32 + quad * 8];
        f32x4 g[6];
#pragma unroll
        for (int nt = 0; nt < 6; nt++) {
            bfrag b0 = *(const bfrag*)&W1s[(nt * 16 + mr) * WP1 + quad * 8];
            bfrag b1 = *(const bfrag*)&W1s[(nt * 16 + mr) * WP1 + 32 + quad * 8];
            f32x4 z = {0.f, 0.f, 0.f, 0.f};
            z = __builtin_amdgcn_mfma_f32_16x16x32_bf16(a0, b0, z, 0, 0, 0);
            z = __builtin_amdgcn_mfma_f32_16x16x32_bf16(a1, b1, z, 0, 0, 0);
            g[nt] = z;
        }
#pragma unroll
        for (int t = 0; t < 2; t++) {
            int c = t * 16 + mr;
            float bi = lb1s[c], bg = lb1s[64 + c], bo = lb1s[96 + c];
#pragma unroll
            for (int r = 0; r < 4; r++) {
                float c1 = fsig(g[t][r] + bi) * ftanh(g[2 + t][r] + bg);
                float h = fsig(g[4 + t][r] + bo) * ftanh(c1);
                bf16 hb = __float2bfloat16(h);
                h1s[(mb + quad * 4 + r) * HP + c] = *(ushort*)&hb;
            }
        }
        LDS_FENCE();
        // LSTM2 gates
        bfrag ha = *(const bfrag*)&h1s[(mb + mr) * HP + quad * 8];
        f32x4 g2[6];
#pragma unroll
        for (int nt = 0; nt < 6; nt++) {
            bfrag b = *(const bfrag*)&W2s[(nt * 16 + mr) * WP2 + quad * 8];
            f32x4 z = {0.f, 0.f, 0.f, 0.f};
            z = __builtin_amdgcn_mfma_f32_16x16x32_bf16(ha, b, z, 0, 0, 0);
            g2[nt] = z;
        }
#pragma unroll
        for (int t = 0; t < 2; t++) {
            int c = t * 16 + mr;
            float bi = lb2s[c], bg = lb2s[64 + c], bo = lb2s[96 + c];
#pragma unroll
            for (int r = 0; r < 4; r++) {
                float c2 = fsig(g2[t][r] + bi) * ftanh(g2[2 + t][r] + bg);
                float h = fsig(g2[4 + t][r] + bo) * ftanh(c2);
                bf16 hb = __float2bfloat16(h);
                h2s[(mb + quad * 4 + r) * HP + c] = *(ushort*)&hb;
            }
        }
        LDS_FENCE();
        // fc1 (K=32 from hn1 via F1 cols 0..31, K=32 from hn2 via cols 32..63)
        bfrag hb2 = *(const bfrag*)&h2s[(mb + mr) * HP + quad * 8];
        f32x4 zt[2];
#pragma unroll
        for (int nt = 0; nt < 2; nt++) {
            bfrag f0 = *(const bfrag*)&F1s[(nt * 16 + mr) * FP1 + quad * 8];
            bfrag f1 = *(const bfrag*)&F1s[(nt * 16 + mr) * FP1 + 32 + quad * 8];
            f32x4 z = {0.f, 0.f, 0.f, 0.f};
            z = __builtin_amdgcn_mfma_f32_16x16x32_bf16(ha, f0, z, 0, 0, 0);
            z = __builtin_amdgcn_mfma_f32_16x16x32_bf16(hb2, f1, z, 0, 0, 0);
            zt[nt] = z;
        }
        // epilogue: relu(z + fc1c) . fw2, reduce over 32 cols
#pragma unroll
        for (int r = 0; r < 4; r++) {
            float s = 0.f;
#pragma unroll
            for (int t = 0; t < 2; t++) {
                int j = t * 16 + mr;
                s += fmaxf(zt[t][r] + fc1s[j], 0.f) * fw2s[j];
            }
            s += __shfl_xor(s, 1); s += __shfl_xor(s, 2);
            s += __shfl_xor(s, 4); s += __shfl_xor(s, 8);
            int node = blockIdx.x * 128 + mb + quad * 4 + r;
            if (mr == 0 && node < N_NODES) out[node] = s + fb2v;
        }
    }
}

extern "C" void kernel_launch(void* const* d_in, const int* in_sizes, int n_in,
                              void* d_out, int out_size, void* d_ws, size_t ws_size,
                              hipStream_t stream) {
    const float* x    = (const float*)d_in[0];
    const int*   ei   = (const int*)d_in[1];
    const float* ew   = (const float*)d_in[2];
    const float* w1   = (const float*)d_in[3];
    const float* b1   = (const float*)d_in[4];
    const float* g1   = (const float*)d_in[5];
    const float* be1  = (const float*)d_in[6];
    const float* w2   = (const float*)d_in[7];
    const float* b2   = (const float*)d_in[8];
    const float* g2   = (const float*)d_in[9];
    const float* be2  = (const float*)d_in[10];
    const float* wih1 = (const float*)d_in[11];
    const float* bih1 = (const float*)d_in[13];
    const float* bhh1 = (const float*)d_in[14];
    const float* wih2 = (const float*)d_in[15];
    const float* bih2 = (const float*)d_in[17];
    const float* bhh2 = (const float*)d_in[18];
    const float* fw1  = (const float*)d_in[19];
    const float* fb1  = (const float*)d_in[20];
    const float* fw2  = (const float*)d_in[21];
    const float* fb2  = (const float*)d_in[22];
    float* out = (float*)d_out;

    // ---- workspace layout (40.5 MB; proven ws >= 41.1 MB from r3/r4) -------
    char* ws = (char*)d_ws;
    float* stats = (float*)ws;                          // 576 floats @ 0
    float* xsum   = stats + 0;
    float* bn1sum = stats + 32;
    float* bn1sq  = stats + 64;
    float* bn2sum = stats + 96;
    float* bn2sq  = stats + 128;
    float* scale1 = stats + 160;
    float* shift1 = stats + 192;
    float* scale2 = stats + 224;
    float* shift2 = stats + 256;
    float* fc1c   = stats + 288;
    float* lb1    = stats + 320;
    float* lb2    = stats + 448;
    ull*   pk    = (ull*)  (ws + 4096);                 // 100000 ull -> 804,096
    int*   bsum  = (int*)  (ws + 804096);               // 391 i
    int*   bbase = (int*)  (ws + 808192);               // 391 i
    int*   off   = (int*)  (ws + 1048576);              // 100001 i -> 1,448,580
    float* deg   = (float*)(ws + 1572864);              // 100000 f -> 1,972,864
    int2*  epk   = (int2*) (ws + 2097152);              // 1.6M int2 -> 14,897,152
    int*   rank  = (int*)  (ws + 14897152);             // 1.6M i -> 21,297,152
    bf16*  A     = (bf16*) (ws + 21297152);             // 6.4MB -> 27,697,152
    bf16*  H     = (bf16*) (ws + 27697152);             // 6.4MB -> 34,097,152
    bf16*  B     = (bf16*) (ws + 34097152);             // 6.4MB -> 40,497,152

    if (ws_size < 40497152ull) {
        k_marker<<<(N_NODES + 255) / 256, 256, 0, stream>>>(out, N_NODES, 911.f);
        return;
    }

    // zero stats + pk in one shot (bytes 0 .. 804,096)
    k_zero_f<<<786, 256, 0, stream>>>(stats, 201024);

    k_hist<<<6250, 256, 0, stream>>>(ei, ew, pk, rank);
    k_bsum<<<SCAN_BLOCKS, 256, 0, stream>>>(pk, bsum);
    k_bscan<<<1, 512, 0, stream>>>(bsum, bbase);
    k_scan3<<<SCAN_BLOCKS, 256, 0, stream>>>(pk, bbase, off, deg);
    k_scatter<<<6250, 256, 0, stream>>>(ei, ew, deg, off, rank, epk);
    k_xmean<<<400, 256, 0, stream>>>(x, xsum);
    k_xw1<<<12500, 256, 0, stream>>>(x, w1, A);
    k_gcn<<<2048, 256, 0, stream>>>(off, epk, A, deg, b1, B, bn1sum, bn1sq);
    k_fin1<<<1, 64, 0, stream>>>(bn1sum, bn1sq, g1, be1, scale1, shift1);
    k_aff_xw<<<12500, 256, 0, stream>>>(B, scale1, shift1, w2, H, A);
    k_gcn<<<2048, 256, 0, stream>>>(off, epk, A, deg, b2, B, bn2sum, bn2sq);
    k_fin2<<<1, 128, 0, stream>>>(bn2sum, bn2sq, g2, be2, xsum, fw1, fb1,
                                  bih1, bhh1, bih2, bhh2,
                                  scale2, shift2, fc1c, lb1, lb2);
    k_final<<<782, 256, 0, stream>>>(H, B, scale2, shift2, wih1, wih2,
                                     fw1, fw2, fb2, fc1c, lb1, lb2, out);
}

// Round 15
// 443.863 us; speedup vs baseline: 1.1258x; 1.0226x over previous
//
#include <hip/hip_runtime.h>
#include <hip/hip_bf16.h>

#define N_NODES 100000
#define N_EDGES 1600000
#define BN_EPS 1e-5f
#define SCAN_BLOCKS 391   // ceil(100000/256)

typedef __hip_bfloat16 bf16;
typedef unsigned long long ull;
typedef float v2f __attribute__((ext_vector_type(2)));
typedef short bfrag __attribute__((ext_vector_type(8)));   // 8 bf16 = 4 VGPRs
typedef float f32x4 __attribute__((ext_vector_type(4)));

__device__ __forceinline__ float b2f(bf16 v) { return __bfloat162float(v); }
__device__ __forceinline__ float frcp(float x) { return __builtin_amdgcn_rcpf(x); }
__device__ __forceinline__ float fsig(float x) { return frcp(1.0f + __expf(-x)); }
__device__ __forceinline__ float ftanh(float x) {
    return 1.0f - 2.0f * frcp(__expf(2.0f * x) + 1.0f);
}
__device__ __forceinline__ float bfr(uint u) { return __uint_as_float(u << 16); }
__device__ __forceinline__ v2f up(uint u) {
    return (v2f){__uint_as_float(u << 16), __uint_as_float(u & 0xffff0000u)};
}
__device__ __forceinline__ v2f vfma(v2f a, v2f b, v2f c) {
    return __builtin_elementwise_fma(a, b, c);
}
__device__ __forceinline__ uint pk2(const float* p) {
    bf16 a = __float2bfloat16(p[0]), b = __float2bfloat16(p[1]);
    return (uint)*(ushort*)&a | ((uint)*(ushort*)&b << 16);
}
__device__ __forceinline__ uint pkv(v2f v) {
    bf16 a = __float2bfloat16(v.x), b = __float2bfloat16(v.y);
    return (uint)*(ushort*)&a | ((uint)*(ushort*)&b << 16);
}
#define LDS_FENCE() __asm__ volatile("s_waitcnt lgkmcnt(0)" ::: "memory")

// ---- utility ---------------------------------------------------------------
__global__ void k_zero_f(float* __restrict__ p, int n) {
    int i = blockIdx.x * 256 + threadIdx.x;
    if (i < n) p[i] = 0.f;
}
__global__ void k_marker(float* __restrict__ p, int n, float v) {
    int i = blockIdx.x * 256 + threadIdx.x;
    if (i < n) p[i] = v;
}

// ---- packed histogram: pk[d] += (1<<48)|fx(ew); rank = old count -----------
__global__ void k_hist(const int* __restrict__ ei, const float* __restrict__ ew,
                       ull* __restrict__ pk, int* __restrict__ rank) {
    int e = blockIdx.x * 256 + threadIdx.x;
    if (e < N_EDGES) {
        int d = ei[N_EDGES + e];
        ull v = (1ull << 48) | (ull)((double)ew[e] * 4294967296.0);
        ull old = atomicAdd(&pk[d], v);
        rank[e] = (int)(old >> 48);
    }
}

// ---- scan stage 1: per-block sums of counts --------------------------------
__global__ void k_bsum(const ull* __restrict__ pk, int* __restrict__ bsum) {
    __shared__ int s[256];
    int idx = blockIdx.x * 256 + threadIdx.x;
    s[threadIdx.x] = (idx < N_NODES) ? (int)(pk[idx] >> 48) : 0;
    __syncthreads();
    for (int st = 128; st >= 1; st >>= 1) {
        if (threadIdx.x < st) s[threadIdx.x] += s[threadIdx.x + st];
        __syncthreads();
    }
    if (threadIdx.x == 0) bsum[blockIdx.x] = s[0];
}

// ---- scan stage 2 (fused): block base via reduction + local scan -> off ----
__global__ void k_scan3(const ull* __restrict__ pk, const int* __restrict__ bsum,
                        int* __restrict__ off, float* __restrict__ deg) {
    __shared__ int red[256];
    __shared__ int wsum[4];
    int tid = threadIdx.x;
    int acc = 0;
    for (int i = tid; i < SCAN_BLOCKS; i += 256)
        if (i < blockIdx.x) acc += bsum[i];
    red[tid] = acc; __syncthreads();
    for (int st = 128; st >= 1; st >>= 1) {
        if (tid < st) red[tid] += red[tid + st];
        __syncthreads();
    }
    int bbase = red[0];
    int idx = blockIdx.x * 256 + tid;
    int lane = tid & 63, w = tid >> 6;
    ull pv = (idx < N_NODES) ? pk[idx] : 0ull;
    int c = (int)(pv >> 48);
    int s = c;
    for (int d = 1; d < 64; d <<= 1) {
        int u = __shfl_up(s, d, 64);
        if (lane >= d) s += u;
    }
    if (lane == 63) wsum[w] = s;
    __syncthreads();
    int wb = 0;
    for (int i = 0; i < w; i++) wb += wsum[i];
    int e = bbase + wb + s - c;                  // exclusive
    if (idx < N_NODES) {
        off[idx] = e;
        deg[idx] = (float)((double)(pv & 0xFFFFFFFFFFFFull) * (1.0 / 4294967296.0));
    }
    if (idx == 0) off[N_NODES] = N_EDGES;        // all dst are in-range
}

// ---- scatter edges into CSR slots as {src, norm} — NO atomics --------------
__global__ void k_scatter(const int* __restrict__ ei, const float* __restrict__ ew,
                          const float* __restrict__ deg, const int* __restrict__ off,
                          const int* __restrict__ rank, int2* __restrict__ epk) {
    int e = blockIdx.x * 256 + threadIdx.x;
    if (e < N_EDGES) {
        int s = ei[e], d = ei[N_EDGES + e];
        float nm = ew[e] * rsqrtf((deg[s] + 1.0f) * (deg[d] + 1.0f));
        epk[off[d] + rank[e]] = make_int2(s, __float_as_int(nm));
    }
}

// ---- column sums of x (for skip_avg) ---------------------------------------
__global__ void k_xmean(const float* __restrict__ x, float* __restrict__ xsum) {
    __shared__ float s[256];
    int f = threadIdx.x & 31, rg = threadIdx.x >> 5;
    float acc = 0.f;
    for (int n = blockIdx.x * 8 + rg; n < N_NODES; n += gridDim.x * 8)
        acc += x[n * 32 + f];
    s[threadIdx.x] = acc; __syncthreads();
    for (int st = 128; st >= 32; st >>= 1) {
        if (threadIdx.x < st) s[threadIdx.x] += s[threadIdx.x + st];
        __syncthreads();
    }
    if (threadIdx.x < 32) atomicAdd(&xsum[threadIdx.x], s[threadIdx.x]);
}

// ---- A = x @ W1 (fp32 in, bf16 out) ----------------------------------------
__global__ void k_xw1(const float* __restrict__ x, const float* __restrict__ w,
                      bf16* __restrict__ A) {
    __shared__ float Ws[32 * 33];
    __shared__ float xs[256];
    for (int i = threadIdx.x; i < 1024; i += 256)
        Ws[(i >> 5) * 33 + (i & 31)] = w[i];
    long base = (long)blockIdx.x * 256;
    xs[threadIdx.x] = x[base + threadIdx.x];
    __syncthreads();
    int r = threadIdx.x >> 5, h = threadIdx.x & 31;
    float acc = 0.f;
#pragma unroll
    for (int f = 0; f < 32; f++) acc += xs[r * 32 + f] * Ws[f * 33 + h];
    A[base + threadIdx.x] = __float2bfloat16(acc);
}

// ---- pull-mode GCN: 16 lanes/node, uint (2-feature) gathers, unroll 4 ------
__global__ __launch_bounds__(256) void k_gcn(
    const int* __restrict__ off, const int2* __restrict__ epk,
    const bf16* __restrict__ A, const float* __restrict__ deg,
    const float* __restrict__ bias, bf16* __restrict__ B,
    float* __restrict__ sum, float* __restrict__ sq) {
    __shared__ v2f s1[256], s2[256];
    const uint* Au = (const uint*)A;
    uint* Bu = (uint*)B;
    int tid = threadIdx.x, fp = tid & 15, g = tid >> 4;
    v2f bv = (v2f){bias[2 * fp], bias[2 * fp + 1]};
    v2f a1 = (v2f)0.f, a2 = (v2f)0.f;
    for (int n = blockIdx.x * 16 + g; n < N_NODES; n += gridDim.x * 16) {
        int lo = off[n], hi = off[n + 1];
        v2f acc0 = (v2f)0.f, acc1 = (v2f)0.f, acc2 = (v2f)0.f, acc3 = (v2f)0.f;
        int p = lo;
        for (; p + 3 < hi; p += 4) {
            int2 e0 = epk[p], e1 = epk[p + 1], e2 = epk[p + 2], e3 = epk[p + 3];
            float n0 = __int_as_float(e0.y), n1 = __int_as_float(e1.y);
            float n2 = __int_as_float(e2.y), n3 = __int_as_float(e3.y);
            acc0 = vfma(up(Au[(long)e0.x * 16 + fp]), (v2f){n0, n0}, acc0);
            acc1 = vfma(up(Au[(long)e1.x * 16 + fp]), (v2f){n1, n1}, acc1);
            acc2 = vfma(up(Au[(long)e2.x * 16 + fp]), (v2f){n2, n2}, acc2);
            acc3 = vfma(up(Au[(long)e3.x * 16 + fp]), (v2f){n3, n3}, acc3);
        }
        for (; p < hi; p++) {
            int2 e0 = epk[p];
            float n0 = __int_as_float(e0.y);
            acc0 = vfma(up(Au[(long)e0.x * 16 + fp]), (v2f){n0, n0}, acc0);
        }
        float si = frcp(deg[n] + 1.0f);
        v2f v = vfma(up(Au[(long)n * 16 + fp]), (v2f){si, si},
                     (acc0 + acc1) + (acc2 + acc3)) + bv;
        v.x = fmaxf(v.x, 0.f); v.y = fmaxf(v.y, 0.f);
        Bu[(long)n * 16 + fp] = pkv(v);
        a1 += v; a2 += v * v;
    }
    s1[tid] = a1; s2[tid] = a2; __syncthreads();
    for (int st = 128; st >= 16; st >>= 1) {
        if (tid < st) { s1[tid] += s1[tid + st]; s2[tid] += s2[tid + st]; }
        __syncthreads();
    }
    if (tid < 16) {
        atomicAdd(&sum[2 * tid], s1[tid].x); atomicAdd(&sum[2 * tid + 1], s1[tid].y);
        atomicAdd(&sq[2 * tid], s2[tid].x);  atomicAdd(&sq[2 * tid + 1], s2[tid].y);
    }
}

// ---- H = affine(B) (bf16); A = H @ W2 (bf16); BN1 finalize fused -----------
__global__ void k_aff_xw(const bf16* __restrict__ B, const float* __restrict__ sum,
                         const float* __restrict__ sq, const float* __restrict__ g,
                         const float* __restrict__ be, const float* __restrict__ w,
                         bf16* __restrict__ H, bf16* __restrict__ A) {
    __shared__ float Ws[32 * 33];
    __shared__ float hs[256];
    __shared__ float sc[32], sh[32];
    int tid = threadIdx.x;
    if (tid < 32) {
        float mu = sum[tid] / (float)N_NODES;
        float var = sq[tid] / (float)N_NODES - mu * mu;
        float rs = rsqrtf(var + BN_EPS) * g[tid];
        sc[tid] = rs;
        sh[tid] = be[tid] - mu * rs;
    }
    for (int i = tid; i < 1024; i += 256)
        Ws[(i >> 5) * 33 + (i & 31)] = w[i];
    __syncthreads();
    long base = (long)blockIdx.x * 256;
    int f = tid & 31;
    float h = b2f(B[base + tid]) * sc[f] + sh[f];
    H[base + tid] = __float2bfloat16(h);
    hs[tid] = h;
    __syncthreads();
    int r = tid >> 5, hc = tid & 31;
    float acc = 0.f;
#pragma unroll
    for (int k = 0; k < 32; k++) acc += hs[r * 32 + k] * Ws[k * 33 + hc];
    A[base + tid] = __float2bfloat16(acc);
}

// ---- per-node dense stack via MFMA; BN2/fc1-const/bias finalize fused ------
// 128 nodes/block, 4 waves, each wave owns 2 disjoint 16-node M-tiles.
// Layouts (verified): A[m=lane&15][k=quad*8+j], B[k=quad*8+j][n=lane&15],
// C/D[row=quad*4+r][col=lane&15].
#define CATP 72
#define WP1  72
#define WP2  40
#define FP1  72
#define HP   40
__global__ __launch_bounds__(256) void k_final(
    const bf16* __restrict__ Hb, const bf16* __restrict__ Bb,
    const float* __restrict__ bn2sum, const float* __restrict__ bn2sq,
    const float* __restrict__ g2, const float* __restrict__ be2,
    const float* __restrict__ xsum,
    const float* __restrict__ wih1, const float* __restrict__ wih2,
    const float* __restrict__ fw1, const float* __restrict__ fw2,
    const float* __restrict__ fb2, const float* __restrict__ fb1,
    const float* __restrict__ bih1, const float* __restrict__ bhh1,
    const float* __restrict__ bih2, const float* __restrict__ bhh2,
    float* __restrict__ out) {
    __shared__ ushort cat[128 * CATP];
    __shared__ ushort W1s[96 * WP1];
    __shared__ ushort W2s[96 * WP2];
    __shared__ ushort F1s[32 * FP1];
    __shared__ ushort h1s[128 * HP];
    __shared__ ushort h2s[128 * HP];
    __shared__ float lb1s[128], lb2s[128], fc1s[32], fw2s[32], sc2[32], sh2[32];
    int tid = threadIdx.x;
    if (tid < 128) { lb1s[tid] = bih1[tid] + bhh1[tid]; lb2s[tid] = bih2[tid] + bhh2[tid]; }
    if (tid >= 128 && tid < 160) {
        int t = tid - 128;
        float mu = bn2sum[t] / (float)N_NODES;
        float var = bn2sq[t] / (float)N_NODES - mu * mu;
        float rs = rsqrtf(var + BN_EPS) * g2[t];
        sc2[t] = rs;
        sh2[t] = be2[t] - mu * rs;
        fw2s[t] = fw2[t];
        float c = fb1[t];
        for (int f = 0; f < 32; f++)
            c += (xsum[f] / (float)N_NODES) * fw1[t * 96 + 64 + f];
        fc1s[t] = c;
    }
    // W1s rows = gate-cols n: 0..31 -> wih1 row n (i), 32..63 -> 64+(n-32) (g),
    // 64..95 -> 96+(n-64) (o). Same mapping for W2s/wih2.
    for (int i = tid; i < 96 * 8; i += 256) {
        int row = i >> 3, q = i & 7;
        int c = row & 31, t = row >> 5;
        int srow = (t == 0) ? c : ((t == 1) ? 64 + c : 96 + c);
        const float* b = wih1 + srow * 64 + q * 8;
        *(uint4*)&W1s[row * WP1 + q * 8] =
            make_uint4(pk2(b), pk2(b + 2), pk2(b + 4), pk2(b + 6));
    }
    for (int i = tid; i < 96 * 4; i += 256) {
        int row = i >> 2, q = i & 3;
        int c = row & 31, t = row >> 5;
        int srow = (t == 0) ? c : ((t == 1) ? 64 + c : 96 + c);
        const float* b = wih2 + srow * 32 + q * 8;
        *(uint4*)&W2s[row * WP2 + q * 8] =
            make_uint4(pk2(b), pk2(b + 2), pk2(b + 4), pk2(b + 6));
    }
    for (int i = tid; i < 32 * 8; i += 256) {
        int row = i >> 3, q = i & 7;
        const float* b = fw1 + row * 96 + q * 8;
        *(uint4*)&F1s[row * FP1 + q * 8] =
            make_uint4(pk2(b), pk2(b + 2), pk2(b + 4), pk2(b + 6));
    }
    __syncthreads();
    // ---- stage cat[node][0..63] = [H | affine(B)] --------------------------
    {
        int ni = tid >> 1, hf = tid & 1;
        int node = blockIdx.x * 128 + ni;
        int nc = node < N_NODES ? node : N_NODES - 1;
        const uint4* src = (const uint4*)((const ushort*)(hf ? Bb : Hb) + (long)nc * 32);
        ushort* dst = &cat[ni * CATP + hf * 32];
        if (hf == 0) {
#pragma unroll
            for (int q = 0; q < 4; q++) *(uint4*)(dst + q * 8) = src[q];
        } else {
#pragma unroll
            for (int q = 0; q < 4; q++) {
                uint4 v = src[q];
                uint w[4] = {v.x, v.y, v.z, v.w};
                uint o[4];
#pragma unroll
                for (int r = 0; r < 4; r++) {
                    int e = q * 8 + r * 2;
                    o[r] = pkv(vfma(up(w[r]), (v2f){sc2[e], sc2[e + 1]},
                                    (v2f){sh2[e], sh2[e + 1]}));
                }
                *(uint4*)(dst + q * 8) = make_uint4(o[0], o[1], o[2], o[3]);
            }
        }
    }
    __syncthreads();
    // ---- compute: wave wv owns M-tiles wv*2, wv*2+1 ------------------------
    int l = tid & 63, wv = tid >> 6;
    int quad = l >> 4, mr = l & 15;
    float fb2v = fb2[0];
#pragma unroll
    for (int it = 0; it < 2; it++) {
        int mt = wv * 2 + it;
        int mb = mt * 16;
        // LSTM1 gates
        bfrag a0 = *(const bfrag*)&cat[(mb + mr) * CATP + quad * 8];
        bfrag a1 = *(const bfrag*)&cat[(mb + mr) * CATP + 32 + quad * 8];
        f32x4 g[6];
#pragma unroll
        for (int nt = 0; nt < 6; nt++) {
            bfrag b0 = *(const bfrag*)&W1s[(nt * 16 + mr) * WP1 + quad * 8];
            bfrag b1 = *(const bfrag*)&W1s[(nt * 16 + mr) * WP1 + 32 + quad * 8];
            f32x4 z = {0.f, 0.f, 0.f, 0.f};
            z = __builtin_amdgcn_mfma_f32_16x16x32_bf16(a0, b0, z, 0, 0, 0);
            z = __builtin_amdgcn_mfma_f32_16x16x32_bf16(a1, b1, z, 0, 0, 0);
            g[nt] = z;
        }
#pragma unroll
        for (int t = 0; t < 2; t++) {
            int c = t * 16 + mr;
            float bi = lb1s[c], bg = lb1s[64 + c], bo = lb1s[96 + c];
#pragma unroll
            for (int r = 0; r < 4; r++) {
                float c1 = fsig(g[t][r] + bi) * ftanh(g[2 + t][r] + bg);
                float h = fsig(g[4 + t][r] + bo) * ftanh(c1);
                bf16 hb = __float2bfloat16(h);
                h1s[(mb + quad * 4 + r) * HP + c] = *(ushort*)&hb;
            }
        }
        LDS_FENCE();
        // LSTM2 gates
        bfrag ha = *(const bfrag*)&h1s[(mb + mr) * HP + quad * 8];
        f32x4 g2r[6];
#pragma unroll
        for (int nt = 0; nt < 6; nt++) {
            bfrag b = *(const bfrag*)&W2s[(nt * 16 + mr) * WP2 + quad * 8];
            f32x4 z = {0.f, 0.f, 0.f, 0.f};
            z = __builtin_amdgcn_mfma_f32_16x16x32_bf16(ha, b, z, 0, 0, 0);
            g2r[nt] = z;
        }
#pragma unroll
        for (int t = 0; t < 2; t++) {
            int c = t * 16 + mr;
            float bi = lb2s[c], bg = lb2s[64 + c], bo = lb2s[96 + c];
#pragma unroll
            for (int r = 0; r < 4; r++) {
                float c2 = fsig(g2r[t][r] + bi) * ftanh(g2r[2 + t][r] + bg);
                float h = fsig(g2r[4 + t][r] + bo) * ftanh(c2);
                bf16 hb = __float2bfloat16(h);
                h2s[(mb + quad * 4 + r) * HP + c] = *(ushort*)&hb;
            }
        }
        LDS_FENCE();
        // fc1 (K=32 from hn1 via F1 cols 0..31, K=32 from hn2 via cols 32..63)
        bfrag hb2 = *(const bfrag*)&h2s[(mb + mr) * HP + quad * 8];
        f32x4 zt[2];
#pragma unroll
        for (int nt = 0; nt < 2; nt++) {
            bfrag f0 = *(const bfrag*)&F1s[(nt * 16 + mr) * FP1 + quad * 8];
            bfrag f1 = *(const bfrag*)&F1s[(nt * 16 + mr) * FP1 + 32 + quad * 8];
            f32x4 z = {0.f, 0.f, 0.f, 0.f};
            z = __builtin_amdgcn_mfma_f32_16x16x32_bf16(ha, f0, z, 0, 0, 0);
            z = __builtin_amdgcn_mfma_f32_16x16x32_bf16(hb2, f1, z, 0, 0, 0);
            zt[nt] = z;
        }
        // epilogue: relu(z + fc1c) . fw2, reduce over 32 cols
#pragma unroll
        for (int r = 0; r < 4; r++) {
            float s = 0.f;
#pragma unroll
            for (int t = 0; t < 2; t++) {
                int j = t * 16 + mr;
                s += fmaxf(zt[t][r] + fc1s[j], 0.f) * fw2s[j];
            }
            s += __shfl_xor(s, 1); s += __shfl_xor(s, 2);
            s += __shfl_xor(s, 4); s += __shfl_xor(s, 8);
            int node = blockIdx.x * 128 + mb + quad * 4 + r;
            if (mr == 0 && node < N_NODES) out[node] = s + fb2v;
        }
    }
}

extern "C" void kernel_launch(void* const* d_in, const int* in_sizes, int n_in,
                              void* d_out, int out_size, void* d_ws, size_t ws_size,
                              hipStream_t stream) {
    const float* x    = (const float*)d_in[0];
    const int*   ei   = (const int*)d_in[1];
    const float* ew   = (const float*)d_in[2];
    const float* w1   = (const float*)d_in[3];
    const float* b1   = (const float*)d_in[4];
    const float* g1   = (const float*)d_in[5];
    const float* be1  = (const float*)d_in[6];
    const float* w2   = (const float*)d_in[7];
    const float* b2   = (const float*)d_in[8];
    const float* g2   = (const float*)d_in[9];
    const float* be2  = (const float*)d_in[10];
    const float* wih1 = (const float*)d_in[11];
    const float* bih1 = (const float*)d_in[13];
    const float* bhh1 = (const float*)d_in[14];
    const float* wih2 = (const float*)d_in[15];
    const float* bih2 = (const float*)d_in[17];
    const float* bhh2 = (const float*)d_in[18];
    const float* fw1  = (const float*)d_in[19];
    const float* fb1  = (const float*)d_in[20];
    const float* fw2  = (const float*)d_in[21];
    const float* fb2  = (const float*)d_in[22];
    float* out = (float*)d_out;

    // ---- workspace layout (40.5 MB; proven ws >= 41.1 MB from r3/r4) -------
    char* ws = (char*)d_ws;
    float* stats = (float*)ws;                          // 160 floats used
    float* xsum   = stats + 0;
    float* bn1sum = stats + 32;
    float* bn1sq  = stats + 64;
    float* bn2sum = stats + 96;
    float* bn2sq  = stats + 128;
    ull*   pk    = (ull*)  (ws + 4096);                 // 100000 ull -> 804,096
    int*   bsum  = (int*)  (ws + 804096);               // 391 i
    int*   off   = (int*)  (ws + 1048576);              // 100001 i -> 1,448,580
    float* deg   = (float*)(ws + 1572864);              // 100000 f -> 1,972,864
    int2*  epk   = (int2*) (ws + 2097152);              // 1.6M int2 -> 14,897,152
    int*   rank  = (int*)  (ws + 14897152);             // 1.6M i -> 21,297,152
    bf16*  A     = (bf16*) (ws + 21297152);             // 6.4MB -> 27,697,152
    bf16*  H     = (bf16*) (ws + 27697152);             // 6.4MB -> 34,097,152
    bf16*  B     = (bf16*) (ws + 34097152);             // 6.4MB -> 40,497,152

    if (ws_size < 40497152ull) {
        k_marker<<<(N_NODES + 255) / 256, 256, 0, stream>>>(out, N_NODES, 911.f);
        return;
    }

    // zero stats + pk in one shot (bytes 0 .. 804,096)
    k_zero_f<<<786, 256, 0, stream>>>(stats, 201024);

    k_hist<<<6250, 256, 0, stream>>>(ei, ew, pk, rank);
    k_bsum<<<SCAN_BLOCKS, 256, 0, stream>>>(pk, bsum);
    k_scan3<<<SCAN_BLOCKS, 256, 0, stream>>>(pk, bsum, off, deg);
    k_scatter<<<6250, 256, 0, stream>>>(ei, ew, deg, off, rank, epk);
    k_xmean<<<400, 256, 0, stream>>>(x, xsum);
    k_xw1<<<12500, 256, 0, stream>>>(x, w1, A);
    k_gcn<<<2048, 256, 0, stream>>>(off, epk, A, deg, b1, B, bn1sum, bn1sq);
    k_aff_xw<<<12500, 256, 0, stream>>>(B, bn1sum, bn1sq, g1, be1, w2, H, A);
    k_gcn<<<2048, 256, 0, stream>>>(off, epk, A, deg, b2, B, bn2sum, bn2sq);
    k_final<<<782, 256, 0, stream>>>(H, B, bn2sum, bn2sq, g2, be2, xsum,
                                     wih1, wih2, fw1, fw2, fb2, fb1,
                                     bih1, bhh1, bih2, bhh2, out);
}